// Round 1
// baseline (3671.447 us; speedup 1.0000x reference)
//
#include <hip/hip_runtime.h>

#define B_ 4
#define C_ 256
#define N_ 4096
#define INTER_ 32

#define TILE_I 16
#define TILE_J 128
#define KSH_LD 36   // 128 rows x 32 floats, padded to 36 (144B, 16B-aligned, conflict-free b128)
#define PSH_LD 136  // 16 rows x 128 floats, padded to 136 (bank spread 8*i+j)

// ---------------- QKV projection ----------------
// grid.x = 10 chunks * (N/256) tiles * B ; block 256 threads, one position each.
// chunk 0: q (32 outs), chunk 1: k (32 outs), chunks 2..9: v rows (chunk-2)*32..+32
__global__ __launch_bounds__(256) void qkv_kernel(
    const float* __restrict__ x,
    const float* __restrict__ Wq, const float* __restrict__ bq,
    const float* __restrict__ Wk, const float* __restrict__ bk,
    const float* __restrict__ Wv, const float* __restrict__ bv,
    float* __restrict__ q, float* __restrict__ k, float* __restrict__ v)
{
    const int tid = threadIdx.x;
    int idx = blockIdx.x;
    const int chunk = idx % 10; idx /= 10;
    const int tile  = idx % (N_ / 256); idx /= (N_ / 256);
    const int b = idx;
    const int n = tile * 256 + tid;

    const float* W; const float* bias; float* outp;
    if (chunk == 0)      { W = Wq; bias = bq; outp = q + ((size_t)((size_t)b * N_ + n)) * INTER_; }
    else if (chunk == 1) { W = Wk; bias = bk; outp = k + ((size_t)((size_t)b * N_ + n)) * INTER_; }
    else {
        int o0 = (chunk - 2) * 32;
        W = Wv + (size_t)o0 * C_; bias = bv + o0;
        outp = v + ((size_t)((size_t)b * N_ + n)) * C_ + o0;
    }

    __shared__ float wsh[32 * C_];
    #pragma unroll
    for (int t = 0; t < 32; ++t) wsh[tid + 256 * t] = W[tid + 256 * t];
    __syncthreads();

    float acc[32];
    #pragma unroll
    for (int o = 0; o < 32; ++o) acc[o] = bias[o];

    const float* xb = x + ((size_t)b * C_) * N_ + n;
    for (int c = 0; c < C_; ++c) {
        float xv = xb[(size_t)c * N_];
        #pragma unroll
        for (int o = 0; o < 32; ++o) acc[o] += wsh[o * C_ + c] * xv;
    }
    #pragma unroll
    for (int o = 0; o < 32; o += 4) {
        *reinterpret_cast<float4*>(outp + o) =
            make_float4(acc[o], acc[o + 1], acc[o + 2], acc[o + 3]);
    }
}

// ---------------- Flash attention (fp32) ----------------
// grid: (N/TILE_I, B); block 256 = 16 i_local x 16 cslot.
// Each thread owns query i = blk*16 + tid/16 and channels c = (tid%16)*16 .. +16.
__global__ __launch_bounds__(256) void attn_kernel(
    const float* __restrict__ q, const float* __restrict__ k, const float* __restrict__ v,
    const float* __restrict__ x, const float* __restrict__ gamma,
    float* __restrict__ out)
{
    const int tid = threadIdx.x;
    const int i_local = tid >> 4;
    const int cslot   = tid & 15;
    const int b = blockIdx.y;
    const int i = blockIdx.x * TILE_I + i_local;

    __shared__ float ksh[TILE_J * KSH_LD];
    __shared__ float psh[TILE_I * PSH_LD];

    // q row -> registers (32 floats)
    float4 qr[8];
    const float4* qrow = reinterpret_cast<const float4*>(q + ((size_t)((size_t)b * N_ + i)) * INTER_);
    #pragma unroll
    for (int t = 0; t < 8; ++t) qr[t] = qrow[t];

    const float rscale = 0.17677669529663687f; // 1/sqrt(32)
    float m_run = -1e30f;
    float l_run = 0.f;         // per-lane partial (this lane's j-subsets); reduced at end
    float acc[16];
    #pragma unroll
    for (int t = 0; t < 16; ++t) acc[t] = 0.f;

    const float* kb = k + ((size_t)b * N_) * INTER_;
    const float* vb = v + ((size_t)b * N_) * C_;

    for (int jt = 0; jt < N_ / TILE_J; ++jt) {
        const int j0 = jt * TILE_J;

        // stage K tile: 128 rows x 32 floats (coalesced)
        {
            const float* src = kb + (size_t)j0 * INTER_;
            #pragma unroll
            for (int t = 0; t < 16; ++t) {
                int lin = tid + 256 * t;       // 0..4095
                int jj = lin >> 5, o = lin & 31;
                ksh[jj * KSH_LD + o] = src[lin];
            }
        }
        __syncthreads();

        // scores for this thread's 8 j's
        float s[8];
        float tmax = -1e30f;
        #pragma unroll
        for (int mI = 0; mI < 8; ++mI) {
            int jl = cslot + 16 * mI;
            const float4* krow = reinterpret_cast<const float4*>(&ksh[jl * KSH_LD]);
            float d = 0.f;
            #pragma unroll
            for (int t = 0; t < 8; ++t) {
                float4 kv = krow[t];
                d += qr[t].x * kv.x + qr[t].y * kv.y + qr[t].z * kv.z + qr[t].w * kv.w;
            }
            s[mI] = d * rscale;
            tmax = fmaxf(tmax, s[mI]);
        }
        // max over the 16-lane group sharing i
        #pragma unroll
        for (int off = 1; off < 16; off <<= 1)
            tmax = fmaxf(tmax, __shfl_xor(tmax, off));

        const float mnew = fmaxf(m_run, tmax);
        const float corr = __expf(m_run - mnew);
        float lsum = 0.f;
        #pragma unroll
        for (int mI = 0; mI < 8; ++mI) {
            float p = __expf(s[mI] - mnew);
            lsum += p;
            psh[i_local * PSH_LD + cslot + 16 * mI] = p;
        }
        l_run = l_run * corr + lsum;
        m_run = mnew;
        #pragma unroll
        for (int t = 0; t < 16; ++t) acc[t] *= corr;

        // barrier: guards ksh overwrite next iter + makes psh visibility airtight
        __syncthreads();

        // PV: acc[c] += sum_j p_ij * v[j, c]; this thread's 16 contiguous channels
        const float4* vt = reinterpret_cast<const float4*>(vb + (size_t)j0 * C_);
        for (int j = 0; j < TILE_J; ++j) {
            float p = psh[i_local * PSH_LD + j];
            const float4* vrow = vt + (size_t)j * (C_ / 4) + cslot * 4;
            #pragma unroll
            for (int t = 0; t < 4; ++t) {
                float4 vv = vrow[t];
                acc[4 * t + 0] += p * vv.x;
                acc[4 * t + 1] += p * vv.y;
                acc[4 * t + 2] += p * vv.z;
                acc[4 * t + 3] += p * vv.w;
            }
        }
    }

    // total softmax denom for this i (sum partials across the 16-lane group)
    float l_tot = l_run;
    #pragma unroll
    for (int off = 1; off < 16; off <<= 1) l_tot += __shfl_xor(l_tot, off);
    const float inv_l = 1.f / l_tot;
    const float g = gamma[0];

    const size_t base = ((size_t)b * C_) * N_ + (size_t)i;
    #pragma unroll
    for (int t = 0; t < 16; ++t) {
        int c = cslot * 16 + t;
        size_t off = base + (size_t)c * N_;
        out[off] = g * acc[t] * inv_l + x[off];
    }
}

extern "C" void kernel_launch(void* const* d_in, const int* in_sizes, int n_in,
                              void* d_out, int out_size, void* d_ws, size_t ws_size,
                              hipStream_t stream) {
    const float* x     = (const float*)d_in[0];
    const float* Wq    = (const float*)d_in[1];
    const float* bq    = (const float*)d_in[2];
    const float* Wk    = (const float*)d_in[3];
    const float* bk    = (const float*)d_in[4];
    const float* Wv    = (const float*)d_in[5];
    const float* bv    = (const float*)d_in[6];
    const float* gamma = (const float*)d_in[7];
    float* out = (float*)d_out;

    float* ws = (float*)d_ws;
    float* q = ws;                                   // B*N*32
    float* k = q + (size_t)B_ * N_ * INTER_;         // B*N*32
    float* v = k + (size_t)B_ * N_ * INTER_;         // B*N*256

    qkv_kernel<<<dim3(10 * (N_ / 256) * B_), 256, 0, stream>>>(
        x, Wq, bq, Wk, bk, Wv, bv, q, k, v);
    attn_kernel<<<dim3(N_ / TILE_I, B_), 256, 0, stream>>>(
        q, k, v, x, gamma, out);
}

// Round 2
// 457.700 us; speedup vs baseline: 8.0215x; 8.0215x over previous
//
#include <hip/hip_runtime.h>

#define B_ 4
#define C_ 256
#define N_ 4096
#define INTER_ 32

typedef __attribute__((ext_vector_type(8))) short short8;
typedef __attribute__((ext_vector_type(4))) float f32x4;
typedef __attribute__((ext_vector_type(8))) unsigned short us8;

static __device__ __forceinline__ unsigned short f2bf(float f) {
    unsigned int u = __builtin_bit_cast(unsigned int, f);
    u += 0x7fff + ((u >> 16) & 1);   // round-to-nearest-even
    return (unsigned short)(u >> 16);
}

// ---------------- QKV projection ----------------
// grid.x = 10 chunks * (N/256) tiles * B ; block 256 threads, one position each.
// chunk 0: q (32 outs, pre-scaled by 1/sqrt(32), bf16 [B][N][32])
// chunk 1: k (32 outs, bf16 [B][N][32])
// chunks 2..9: v rows (chunk-2)*32..+32 -> bf16 TRANSPOSED Vt [B][C][N]
__global__ __launch_bounds__(256) void qkv_kernel(
    const float* __restrict__ x,
    const float* __restrict__ Wq, const float* __restrict__ bq,
    const float* __restrict__ Wk, const float* __restrict__ bk,
    const float* __restrict__ Wv, const float* __restrict__ bv,
    unsigned short* __restrict__ qb, unsigned short* __restrict__ kb,
    unsigned short* __restrict__ vt)
{
    const int tid = threadIdx.x;
    int idx = blockIdx.x;
    const int chunk = idx % 10; idx /= 10;
    const int tile  = idx % (N_ / 256); idx /= (N_ / 256);
    const int b = idx;
    const int n = tile * 256 + tid;

    const float* W; const float* bias;
    if (chunk == 0)      { W = Wq; bias = bq; }
    else if (chunk == 1) { W = Wk; bias = bk; }
    else {
        int o0 = (chunk - 2) * 32;
        W = Wv + (size_t)o0 * C_; bias = bv + o0;
    }

    __shared__ float wsh[32 * C_];
    #pragma unroll
    for (int t = 0; t < 32; ++t) wsh[tid + 256 * t] = W[tid + 256 * t];
    __syncthreads();

    float acc[32];
    #pragma unroll
    for (int o = 0; o < 32; ++o) acc[o] = bias[o];

    const float* xb = x + ((size_t)b * C_) * N_ + n;
    for (int c = 0; c < C_; ++c) {
        float xv = xb[(size_t)c * N_];
        #pragma unroll
        for (int o = 0; o < 32; ++o) acc[o] += wsh[o * C_ + c] * xv;
    }

    if (chunk == 0) {
        const float rs = 0.17677669529663687f; // 1/sqrt(32), folded into q
        unsigned short t[32];
        #pragma unroll
        for (int o = 0; o < 32; ++o) t[o] = f2bf(acc[o] * rs);
        us8* dst = reinterpret_cast<us8*>(qb + ((size_t)((size_t)b * N_ + n)) * 32);
        #pragma unroll
        for (int g = 0; g < 4; ++g) dst[g] = *reinterpret_cast<us8*>(&t[8 * g]);
    } else if (chunk == 1) {
        unsigned short t[32];
        #pragma unroll
        for (int o = 0; o < 32; ++o) t[o] = f2bf(acc[o]);
        us8* dst = reinterpret_cast<us8*>(kb + ((size_t)((size_t)b * N_ + n)) * 32);
        #pragma unroll
        for (int g = 0; g < 4; ++g) dst[g] = *reinterpret_cast<us8*>(&t[8 * g]);
    } else {
        const int o0 = (chunk - 2) * 32;
        unsigned short* vb_ = vt + ((size_t)b * C_ + o0) * N_ + n;
        #pragma unroll
        for (int o = 0; o < 32; ++o) vb_[(size_t)o * N_] = f2bf(acc[o]); // coalesced across lanes
    }
}

// ---------------- Flash attention, bf16 MFMA ----------------
// grid: (N/16, B); block 256 = 4 waves. Block owns 16 query rows; wave w owns
// V-channels c = w*64 .. +64. Each wave redundantly computes S = Q K^T for the
// 16 rows (cheap: 2 MFMAs/step) and its own softmax copy, then 4 PV MFMAs.
// Per-wave LDS region for the P transpose (S-layout -> A-fragment layout).
// No __syncthreads needed: waves never share state.
__global__ __launch_bounds__(256) void attn_kernel(
    const unsigned short* __restrict__ qb, const unsigned short* __restrict__ kb,
    const unsigned short* __restrict__ vt,
    const float* __restrict__ x, const float* __restrict__ gamma,
    float* __restrict__ out)
{
    const int tid  = threadIdx.x;
    const int wave = tid >> 6;
    const int lane = tid & 63;
    const int h    = lane >> 4;   // 0..3  (k-chunk / row-group selector)
    const int lj   = lane & 15;   // 0..15 (row/col within fragment)
    const int b  = blockIdx.y;
    const int i0 = blockIdx.x * 16;
    const int c0 = wave * 64;

    // P tile per wave: 16 rows (i) x 32 cols (j) bf16, row stride 80 B (20 u32)
    __shared__ unsigned int psh[4][16 * 20];
    unsigned int* pw = &psh[wave][0];

    // Q A-fragment: row i = i0+lj, k = 8h..8h+8 (16 B contiguous)
    short8 qa = *reinterpret_cast<const short8*>(
        qb + (((size_t)b * N_ + i0 + lj) * 32 + 8 * h));

    f32x4 acc[4];
    #pragma unroll
    for (int f = 0; f < 4; ++f) acc[f] = f32x4{0.f, 0.f, 0.f, 0.f};
    float mr[4] = {-1e30f, -1e30f, -1e30f, -1e30f};
    float lr[4] = {0.f, 0.f, 0.f, 0.f};

    const unsigned short* kbb = kb + (size_t)b * N_ * INTER_;
    const unsigned short* vtb = vt + (size_t)b * C_ * N_;

    for (int jt = 0; jt < N_ / 32; ++jt) {
        const int j0 = jt * 32;

        // K B-fragments: frag0 covers actual j = j0 + 2*col, frag1 j = j0 + 2*col+1
        // (interleaved so each lane's two S values are j-adjacent -> packed write)
        short8 kf0 = *reinterpret_cast<const short8*>(
            kbb + ((size_t)(j0 + 2 * lj)     * INTER_ + 8 * h));
        short8 kf1 = *reinterpret_cast<const short8*>(
            kbb + ((size_t)(j0 + 2 * lj + 1) * INTER_ + 8 * h));

        // V B-fragments: col c = c0+16f+lj, k = j0+8h..+8 (16 B contiguous in Vt)
        short8 vf[4];
        #pragma unroll
        for (int f = 0; f < 4; ++f)
            vf[f] = *reinterpret_cast<const short8*>(
                vtb + ((size_t)(c0 + 16 * f + lj) * N_ + j0 + 8 * h));

        const f32x4 z = {0.f, 0.f, 0.f, 0.f};
        f32x4 s0 = __builtin_amdgcn_mfma_f32_16x16x32_bf16(qa, kf0, z, 0, 0, 0);
        f32x4 s1 = __builtin_amdgcn_mfma_f32_16x16x32_bf16(qa, kf1, z, 0, 0, 0);
        // lane holds S[i=4h+r][j0+2*lj] in s0[r], S[i=4h+r][j0+2*lj+1] in s1[r]

        float corr_[4];
        #pragma unroll
        for (int r = 0; r < 4; ++r) {
            float tm = fmaxf(s0[r], s1[r]);
            tm = fmaxf(tm, __shfl_xor(tm, 1));
            tm = fmaxf(tm, __shfl_xor(tm, 2));
            tm = fmaxf(tm, __shfl_xor(tm, 4));
            tm = fmaxf(tm, __shfl_xor(tm, 8));
            const float mn   = fmaxf(mr[r], tm);
            const float corr = __expf(mr[r] - mn);
            const float p0   = __expf(s0[r] - mn);
            const float p1   = __expf(s1[r] - mn);
            mr[r] = mn;
            lr[r] = lr[r] * corr + p0 + p1;     // per-lane partial; reduced at end
            corr_[r] = corr;
            const unsigned int pk =
                (unsigned int)f2bf(p0) | ((unsigned int)f2bf(p1) << 16);
            pw[(4 * h + r) * 20 + lj] = pk;     // P[i][2lj], P[i][2lj+1]
        }
        #pragma unroll
        for (int f = 0; f < 4; ++f)
            #pragma unroll
            for (int r = 0; r < 4; ++r) acc[f][r] *= corr_[r];

        // same-wave LDS write->read ordering
        asm volatile("s_waitcnt lgkmcnt(0)" ::: "memory");

        // P A-fragment: row i = lj, j = 8h..+8 (16 B, stride-80 rows -> 2-way max)
        short8 pa = *reinterpret_cast<const short8*>(
            reinterpret_cast<const unsigned short*>(pw) + lj * 40 + 8 * h);

        #pragma unroll
        for (int f = 0; f < 4; ++f)
            acc[f] = __builtin_amdgcn_mfma_f32_16x16x32_bf16(pa, vf[f], acc[f], 0, 0, 0);
    }

    const float g = gamma[0];
    #pragma unroll
    for (int r = 0; r < 4; ++r) {
        float lt = lr[r];
        lt += __shfl_xor(lt, 1);
        lt += __shfl_xor(lt, 2);
        lt += __shfl_xor(lt, 4);
        lt += __shfl_xor(lt, 8);
        const float inv = 1.f / lt;
        const int i = i0 + 4 * h + r;
        #pragma unroll
        for (int f = 0; f < 4; ++f) {
            const int c = c0 + 16 * f + lj;
            const size_t off = ((size_t)b * C_ + c) * N_ + i;
            out[off] = g * acc[f][r] * inv + x[off];
        }
    }
}

extern "C" void kernel_launch(void* const* d_in, const int* in_sizes, int n_in,
                              void* d_out, int out_size, void* d_ws, size_t ws_size,
                              hipStream_t stream) {
    const float* x     = (const float*)d_in[0];
    const float* Wq    = (const float*)d_in[1];
    const float* bq    = (const float*)d_in[2];
    const float* Wk    = (const float*)d_in[3];
    const float* bk    = (const float*)d_in[4];
    const float* Wv    = (const float*)d_in[5];
    const float* bv    = (const float*)d_in[6];
    const float* gamma = (const float*)d_in[7];
    float* out = (float*)d_out;

    unsigned short* ws = (unsigned short*)d_ws;
    unsigned short* qb = ws;                                   // B*N*32 bf16
    unsigned short* kb = qb + (size_t)B_ * N_ * INTER_;        // B*N*32 bf16
    unsigned short* vt = kb + (size_t)B_ * N_ * INTER_;        // B*C*N bf16 (transposed)

    qkv_kernel<<<dim3(10 * (N_ / 256) * B_), 256, 0, stream>>>(
        x, Wq, bq, Wk, bk, Wv, bv, qb, kb, vt);
    attn_kernel<<<dim3(N_ / 16, B_), 256, 0, stream>>>(
        qb, kb, vt, x, gamma, out);
}

// Round 3
// 277.560 us; speedup vs baseline: 13.2276x; 1.6490x over previous
//
#include <hip/hip_runtime.h>

#define B_ 4
#define C_ 256
#define N_ 4096
#define INTER_ 32

typedef __attribute__((ext_vector_type(8))) short short8;
typedef __attribute__((ext_vector_type(4))) float f32x4;
typedef __attribute__((ext_vector_type(16))) float f32x16;
typedef __attribute__((ext_vector_type(4))) unsigned int u32x4;
typedef __attribute__((ext_vector_type(8))) unsigned short us8;

static __device__ __forceinline__ unsigned short f2bf(float f) {
    unsigned int u = __builtin_bit_cast(unsigned int, f);
    u += 0x7fff + ((u >> 16) & 1);   // round-to-nearest-even
    return (unsigned short)(u >> 16);
}

static __device__ __forceinline__ unsigned int cvtpk(float lo, float hi) {
    unsigned int r;
    asm("v_cvt_pk_bf16_f32 %0, %1, %2" : "=v"(r) : "v"(lo), "v"(hi));
    return r;
}

static __device__ __forceinline__ void pl32swap(unsigned int& a, unsigned int& b) {
    // a[32:63] <-> b[0:31]
    asm("v_permlane32_swap_b32 %0, %1" : "+v"(a), "+v"(b));
}

// ---------------- QKV projection (unchanged from round 2) ----------------
__global__ __launch_bounds__(256) void qkv_kernel(
    const float* __restrict__ x,
    const float* __restrict__ Wq, const float* __restrict__ bq,
    const float* __restrict__ Wk, const float* __restrict__ bk,
    const float* __restrict__ Wv, const float* __restrict__ bv,
    unsigned short* __restrict__ qb, unsigned short* __restrict__ kb,
    unsigned short* __restrict__ vt)
{
    const int tid = threadIdx.x;
    int idx = blockIdx.x;
    const int chunk = idx % 10; idx /= 10;
    const int tile  = idx % (N_ / 256); idx /= (N_ / 256);
    const int b = idx;
    const int n = tile * 256 + tid;

    const float* W; const float* bias;
    if (chunk == 0)      { W = Wq; bias = bq; }
    else if (chunk == 1) { W = Wk; bias = bk; }
    else {
        int o0 = (chunk - 2) * 32;
        W = Wv + (size_t)o0 * C_; bias = bv + o0;
    }

    __shared__ float wsh[32 * C_];
    #pragma unroll
    for (int t = 0; t < 32; ++t) wsh[tid + 256 * t] = W[tid + 256 * t];
    __syncthreads();

    float acc[32];
    #pragma unroll
    for (int o = 0; o < 32; ++o) acc[o] = bias[o];

    const float* xb = x + ((size_t)b * C_) * N_ + n;
    for (int c = 0; c < C_; ++c) {
        float xv = xb[(size_t)c * N_];
        #pragma unroll
        for (int o = 0; o < 32; ++o) acc[o] += wsh[o * C_ + c] * xv;
    }

    if (chunk == 0) {
        const float rs = 0.17677669529663687f; // 1/sqrt(32), folded into q
        unsigned short t[32];
        #pragma unroll
        for (int o = 0; o < 32; ++o) t[o] = f2bf(acc[o] * rs);
        us8* dst = reinterpret_cast<us8*>(qb + ((size_t)((size_t)b * N_ + n)) * 32);
        #pragma unroll
        for (int g = 0; g < 4; ++g) dst[g] = *reinterpret_cast<us8*>(&t[8 * g]);
    } else if (chunk == 1) {
        unsigned short t[32];
        #pragma unroll
        for (int o = 0; o < 32; ++o) t[o] = f2bf(acc[o]);
        us8* dst = reinterpret_cast<us8*>(kb + ((size_t)((size_t)b * N_ + n)) * 32);
        #pragma unroll
        for (int g = 0; g < 4; ++g) dst[g] = *reinterpret_cast<us8*>(&t[8 * g]);
    } else {
        const int o0 = (chunk - 2) * 32;
        unsigned short* vb_ = vt + ((size_t)b * C_ + o0) * N_ + n;
        #pragma unroll
        for (int o = 0; o < 32; ++o) vb_[(size_t)o * N_] = f2bf(acc[o]);
    }
}

// ---------------- Flash attention, swapped-operand 32x32 MFMA ----------------
// grid (N/32, B), block 256 = 4 waves. Block owns 32 query rows (i0..i0+32),
// wave w handles the j-range [w*N/4, (w+1)*N/4) -- a 4-way flash split,
// combined at the end through a 64KB LDS tree.
// Per 32-key step per wave: S^T = mfma32(K, Q) twice (K=32), lane-local online
// softmax (i = lane&31), cvt_pk + permlane32_swap builds P B-frags in-register,
// then 16 PV MFMAs produce O^T[c][i] (i = lane&31 -> lane-local normalization).
__global__ __launch_bounds__(256, 1) void attn_kernel(
    const unsigned short* __restrict__ qb, const unsigned short* __restrict__ kb,
    const unsigned short* __restrict__ vt,
    const float* __restrict__ x, const float* __restrict__ gamma,
    float* __restrict__ out)
{
    const int tid  = threadIdx.x;
    const int wave = tid >> 6;
    const int lane = tid & 63;
    const int l31  = lane & 31;
    const int h2   = lane >> 5;
    const int b  = blockIdx.y;
    const int i0 = blockIdx.x * 32;

    __shared__ f32x4 buf[2][8 * 4 * 64];     // 64 KB combine buffers
    __shared__ float m_sh[4][32], l_sh[4][32];

    const unsigned short* kbb = kb + (size_t)b * N_ * INTER_;
    const unsigned short* vtb = vt + (size_t)b * C_ * N_;

    // Q B-fragments (k0 = 0, 16): B[k=8*h2+t][i=l31]
    short8 qf0 = *reinterpret_cast<const short8*>(
        qb + ((size_t)b * N_ + i0 + l31) * INTER_ + 8 * h2);
    short8 qf1 = *reinterpret_cast<const short8*>(
        qb + ((size_t)b * N_ + i0 + l31) * INTER_ + 8 * h2 + 16);

    f32x16 acc[8];
    #pragma unroll
    for (int g = 0; g < 8; ++g)
        #pragma unroll
        for (int r = 0; r < 16; ++r) acc[g][r] = 0.f;

    float m_run = 0.f;   // valid init: p = e^{s-0}; slow path fixes if s grows
    float l_run = 0.f;   // this lane's partial (its 16 j's); partner added later

    const int jbeg = wave * (N_ / 4);
    const f32x16 z16 = {};

    for (int jt = 0; jt < (N_ / 4) / 32; ++jt) {
        const int j0 = jbeg + jt * 32;

        // K A-fragments: A[row=j=l31][k=8*h2+t]
        short8 ka0 = *reinterpret_cast<const short8*>(
            kbb + (size_t)(j0 + l31) * INTER_ + 8 * h2);
        short8 ka1 = *reinterpret_cast<const short8*>(
            kbb + (size_t)(j0 + l31) * INTER_ + 8 * h2 + 16);

        f32x16 s = __builtin_amdgcn_mfma_f32_32x32x16_bf16(ka0, qf0, z16, 0, 0, 0);
        s = __builtin_amdgcn_mfma_f32_32x32x16_bf16(ka1, qf1, s, 0, 0, 0);
        // lane holds S^T[j_loc][i=l31], j_loc(r) = (r&3) + 8*(r>>2) + 4*h2

        // in-lane max tree over 16
        float a0 = fmaxf(s[0], s[8]),  a1 = fmaxf(s[1], s[9]);
        float a2 = fmaxf(s[2], s[10]), a3 = fmaxf(s[3], s[11]);
        float a4 = fmaxf(s[4], s[12]), a5 = fmaxf(s[5], s[13]);
        float a6 = fmaxf(s[6], s[14]), a7 = fmaxf(s[7], s[15]);
        a0 = fmaxf(a0, a4); a1 = fmaxf(a1, a5); a2 = fmaxf(a2, a6); a3 = fmaxf(a3, a7);
        float smax = fmaxf(fmaxf(a0, a1), fmaxf(a2, a3));

        if (__any(smax > m_run + 5.5f)) {        // defer-max: rare slow path
            float sm2 = fmaxf(smax, __shfl_xor(smax, 32));
            float mnew = fmaxf(m_run, sm2);
            float corr = __expf(m_run - mnew);
            m_run = mnew;
            l_run *= corr;
            #pragma unroll
            for (int g = 0; g < 8; ++g)
                #pragma unroll
                for (int r = 0; r < 16; ++r) acc[g][r] *= corr;
        }

        float p[16];
        float lsum = 0.f;
        #pragma unroll
        for (int r = 0; r < 16; ++r) { p[r] = __expf(s[r] - m_run); lsum += p[r]; }
        l_run += lsum;

        // pack P -> bf16 pairs; permlane32_swap assembles B-frags in-register
        unsigned int X0 = cvtpk(p[0],  p[1]),  X1 = cvtpk(p[2],  p[3]);
        unsigned int Y0 = cvtpk(p[4],  p[5]),  Y1 = cvtpk(p[6],  p[7]);
        unsigned int W0 = cvtpk(p[8],  p[9]),  W1 = cvtpk(p[10], p[11]);
        unsigned int V0 = cvtpk(p[12], p[13]), V1 = cvtpk(p[14], p[15]);
        pl32swap(X0, Y0); pl32swap(X1, Y1);   // kc=0: [X0,X1,Y0,Y1]
        pl32swap(W0, V0); pl32swap(W1, V1);   // kc=1: [W0,W1,V0,V1]
        short8 pb0 = __builtin_bit_cast(short8, u32x4{X0, X1, Y0, Y1});
        short8 pb1 = __builtin_bit_cast(short8, u32x4{W0, W1, V0, V1});

        // PV: acc[g] (O^T tile, c-group g) += V^T A-frag x P B-frag
        #pragma unroll
        for (int g = 0; g < 8; ++g) {
            const unsigned short* vrow = vtb + (size_t)(32 * g + l31) * N_ + j0 + 8 * h2;
            short8 va0 = *reinterpret_cast<const short8*>(vrow);
            short8 va1 = *reinterpret_cast<const short8*>(vrow + 16);
            acc[g] = __builtin_amdgcn_mfma_f32_32x32x16_bf16(va0, pb0, acc[g], 0, 0, 0);
            acc[g] = __builtin_amdgcn_mfma_f32_32x32x16_bf16(va1, pb1, acc[g], 0, 0, 0);
        }
    }

    // ---- 4-way combine across waves ----
    float l_tot = l_run + __shfl_xor(l_run, 32);
    if (lane < 32) { m_sh[wave][lane] = m_run; l_sh[wave][lane] = l_tot; }
    __syncthreads();

    const float M = fmaxf(fmaxf(m_sh[0][l31], m_sh[1][l31]),
                          fmaxf(m_sh[2][l31], m_sh[3][l31]));
    float L = 0.f;
    #pragma unroll
    for (int w = 0; w < 4; ++w) L += __expf(m_sh[w][l31] - M) * l_sh[w][l31];
    const float wgt = __expf(m_run - M);

    if (wave >= 2) {            // waves 2,3 dump scaled acc
        f32x4* dst = buf[wave - 2];
        #pragma unroll
        for (int g = 0; g < 8; ++g)
            #pragma unroll
            for (int r4 = 0; r4 < 4; ++r4) {
                f32x4 t;
                #pragma unroll
                for (int e = 0; e < 4; ++e) t[e] = acc[g][4 * r4 + e] * wgt;
                dst[(g * 4 + r4) * 64 + lane] = t;
            }
    }
    __syncthreads();
    if (wave < 2) {             // waves 0,1 merge partner-pair
        #pragma unroll
        for (int g = 0; g < 8; ++g)
            #pragma unroll
            for (int r4 = 0; r4 < 4; ++r4) {
                f32x4 t = buf[wave][(g * 4 + r4) * 64 + lane];
                #pragma unroll
                for (int e = 0; e < 4; ++e)
                    acc[g][4 * r4 + e] = acc[g][4 * r4 + e] * wgt + t[e];
            }
    }
    if (wave == 1) {            // wave 1 dumps its merged half
        #pragma unroll
        for (int g = 0; g < 8; ++g)
            #pragma unroll
            for (int r4 = 0; r4 < 4; ++r4) {
                f32x4 t;
                #pragma unroll
                for (int e = 0; e < 4; ++e) t[e] = acc[g][4 * r4 + e];
                buf[1][(g * 4 + r4) * 64 + lane] = t;
            }
    }
    __syncthreads();
    if (wave == 0) {            // wave 0 final merge, dump result
        #pragma unroll
        for (int g = 0; g < 8; ++g)
            #pragma unroll
            for (int r4 = 0; r4 < 4; ++r4) {
                f32x4 t = buf[1][(g * 4 + r4) * 64 + lane];
                #pragma unroll
                for (int e = 0; e < 4; ++e) t[e] += acc[g][4 * r4 + e];
                buf[0][(g * 4 + r4) * 64 + lane] = t;
            }
    }
    __syncthreads();

    // ---- epilogue: g-split across waves; i = l31 lane-local ----
    const float gma  = gamma[0];
    const float invL = 1.f / L;
    #pragma unroll
    for (int gi = 0; gi < 2; ++gi) {
        const int gg = 2 * wave + gi;
        #pragma unroll
        for (int r4 = 0; r4 < 4; ++r4) {
            f32x4 v = buf[0][(gg * 4 + r4) * 64 + lane];
            #pragma unroll
            for (int e = 0; e < 4; ++e) {
                const int c = 32 * gg + e + 8 * r4 + 4 * h2;
                const size_t off = ((size_t)b * C_ + c) * N_ + i0 + l31;
                out[off] = gma * v[e] * invL + x[off];
            }
        }
    }
}

extern "C" void kernel_launch(void* const* d_in, const int* in_sizes, int n_in,
                              void* d_out, int out_size, void* d_ws, size_t ws_size,
                              hipStream_t stream) {
    const float* x     = (const float*)d_in[0];
    const float* Wq    = (const float*)d_in[1];
    const float* bq    = (const float*)d_in[2];
    const float* Wk    = (const float*)d_in[3];
    const float* bk    = (const float*)d_in[4];
    const float* Wv    = (const float*)d_in[5];
    const float* bv    = (const float*)d_in[6];
    const float* gamma = (const float*)d_in[7];
    float* out = (float*)d_out;

    unsigned short* ws = (unsigned short*)d_ws;
    unsigned short* qb = ws;                                   // B*N*32 bf16
    unsigned short* kb = qb + (size_t)B_ * N_ * INTER_;        // B*N*32 bf16
    unsigned short* vt = kb + (size_t)B_ * N_ * INTER_;        // B*C*N bf16 (transposed)

    qkv_kernel<<<dim3(10 * (N_ / 256) * B_), 256, 0, stream>>>(
        x, Wq, bq, Wk, bk, Wv, bv, qb, kb, vt);
    attn_kernel<<<dim3(N_ / 32, B_), 256, 0, stream>>>(
        qb, kb, vt, x, gamma, out);
}

// Round 4
// 165.965 us; speedup vs baseline: 22.1218x; 1.6724x over previous
//
#include <hip/hip_runtime.h>

#define B_ 4
#define C_ 256
#define N_ 4096
#define INTER_ 32

typedef __attribute__((ext_vector_type(8))) short short8;
typedef __attribute__((ext_vector_type(4))) float f32x4;
typedef __attribute__((ext_vector_type(16))) float f32x16;
typedef __attribute__((ext_vector_type(4))) unsigned int u32x4;

static __device__ __forceinline__ unsigned short f2bf(float f) {
    unsigned int u = __builtin_bit_cast(unsigned int, f);
    u += 0x7fff + ((u >> 16) & 1);   // round-to-nearest-even
    return (unsigned short)(u >> 16);
}

static __device__ __forceinline__ unsigned int cvtpk(float lo, float hi) {
    unsigned int r;
    asm("v_cvt_pk_bf16_f32 %0, %1, %2" : "=v"(r) : "v"(lo), "v"(hi));
    return r;
}

static __device__ __forceinline__ void pl32swap(unsigned int& a, unsigned int& b) {
    asm("v_permlane32_swap_b32 %0, %1" : "+v"(a), "+v"(b));
}

// ---------------- W prep: concat + bf16 convert ----------------
// wb rows: 0-31 = Wq, 32-63 = Wk, 64-319 = Wv.  [320][256] bf16.
__global__ __launch_bounds__(256) void prep_kernel(
    const float* __restrict__ Wq, const float* __restrict__ Wk,
    const float* __restrict__ Wv, unsigned short* __restrict__ wb)
{
    int i = blockIdx.x * 256 + threadIdx.x;      // 0 .. 320*256-1
    int row = i >> 8, col = i & 255;
    float v;
    if (row < 32)      v = Wq[row * 256 + col];
    else if (row < 64) v = Wk[(row - 32) * 256 + col];
    else               v = Wv[(row - 64) * 256 + col];
    wb[i] = f2bf(v);
}

// ---------------- QKV projection as MFMA GEMM ----------------
// grid = B * N/64 blocks, 256 threads (4 waves). Block stages x-tile
// [64 n][256 c] bf16 transposed in LDS (row stride 258 shorts), then each
// wave computes 5 (chunk, n-sub) units of 32 outs x 32 positions via
// 16x mfma_32x32x16 over k=c. x is read from HBM exactly once.
__global__ __launch_bounds__(256) void qkv_kernel(
    const float* __restrict__ x, const unsigned short* __restrict__ wb,
    const float* __restrict__ bq, const float* __restrict__ bk,
    const float* __restrict__ bv,
    unsigned short* __restrict__ qb, unsigned short* __restrict__ kb,
    unsigned short* __restrict__ vt)
{
    const int tid  = threadIdx.x;
    const int wave = tid >> 6;
    const int lane = tid & 63;
    const int l31  = lane & 31;
    const int h2   = lane >> 5;
    const int b    = blockIdx.x >> 6;        // N/64 = 64 tiles per batch
    const int n0   = (blockIdx.x & 63) * 64;

    __shared__ unsigned int xsh[64 * 129];   // [n][c/2] u32, row stride 129 dwords

    // ---- stage: wave w loads c-rows 64w..64w+63, write transposed ----
    {
        const float* xb = x + ((size_t)b * C_ + 64 * wave) * N_ + n0 + lane;
        unsigned int* dst = xsh + (size_t)lane * 129 + 32 * wave;
        #pragma unroll 8
        for (int s = 0; s < 32; ++s) {
            float v0 = xb[(size_t)(2 * s) * N_];
            float v1 = xb[(size_t)(2 * s + 1) * N_];
            dst[s] = (unsigned int)f2bf(v0) | ((unsigned int)f2bf(v1) << 16);
        }
    }
    __syncthreads();

    const float rs = 0.17677669529663687f;   // 1/sqrt(32) folded into q at store

    #pragma unroll
    for (int u = 0; u < 5; ++u) {
        const int unit = wave + 4 * u;       // 0..19
        const int ch = unit >> 1;            // 0..9
        const int ns = unit & 1;             // n-subtile
        const int ncol = n0 + 32 * ns + l31; // this lane's position

        // acc init = bias
        const float* bias = (ch == 0) ? bq : (ch == 1) ? bk : (bv + (ch - 2) * 32);
        f32x16 acc;
        #pragma unroll
        for (int r = 0; r < 16; ++r)
            acc[r] = bias[(r & 3) + 8 * (r >> 2) + 4 * h2];

        const unsigned short* wrow = wb + ((size_t)(ch * 32 + l31)) * 256 + 8 * h2;
        const unsigned int*   xrow = xsh + (size_t)(32 * ns + l31) * 129 + 4 * h2;

        #pragma unroll
        for (int kk = 0; kk < 16; ++kk) {
            short8 wa = *reinterpret_cast<const short8*>(wrow + 16 * kk);
            short8 xf = *reinterpret_cast<const short8*>(xrow + 8 * kk);
            acc = __builtin_amdgcn_mfma_f32_32x32x16_bf16(wa, xf, acc, 0, 0, 0);
        }

        if (ch < 2) {
            // q/k: [b][n][32] layout; regs 4q..4q+3 are o = 4h2+8q .. +3 contiguous
            unsigned short* dst = (ch ? kb : qb) + ((size_t)b * N_ + ncol) * 32;
            const float sc = ch ? 1.0f : rs;
            #pragma unroll
            for (int q = 0; q < 4; ++q) {
                unsigned int w0 = (unsigned int)f2bf(acc[4 * q] * sc)
                                | ((unsigned int)f2bf(acc[4 * q + 1] * sc) << 16);
                unsigned int w1 = (unsigned int)f2bf(acc[4 * q + 2] * sc)
                                | ((unsigned int)f2bf(acc[4 * q + 3] * sc) << 16);
                unsigned int* p = reinterpret_cast<unsigned int*>(dst + 4 * h2 + 8 * q);
                p[0] = w0; p[1] = w1;
            }
        } else {
            // v: transposed vt[b][c][n]
            #pragma unroll
            for (int r = 0; r < 16; ++r) {
                const int c = (ch - 2) * 32 + (r & 3) + 8 * (r >> 2) + 4 * h2;
                vt[((size_t)b * C_ + c) * N_ + ncol] = f2bf(acc[r]);
            }
        }
    }
}

// ---------------- Flash attention, swapped-operand 32x32 MFMA ----------------
// grid (N/32, B), block 256 = 4 waves (j-split 4-way), phased 32KB combine.
__global__ __launch_bounds__(256, 3) void attn_kernel(
    const unsigned short* __restrict__ qb, const unsigned short* __restrict__ kb,
    const unsigned short* __restrict__ vt,
    const float* __restrict__ x, const float* __restrict__ gamma,
    float* __restrict__ out)
{
    const int tid  = threadIdx.x;
    const int wave = tid >> 6;
    const int lane = tid & 63;
    const int l31  = lane & 31;
    const int h2   = lane >> 5;
    const int b  = blockIdx.y;
    const int i0 = blockIdx.x * 32;

    __shared__ f32x4 buf[8 * 4 * 64];        // 32 KB combine buffer
    __shared__ float m_sh[4][32], l_sh[4][32];

    const unsigned short* kbb = kb + (size_t)b * N_ * INTER_;
    const unsigned short* vtb = vt + (size_t)b * C_ * N_;

    // Q B-fragments (k0 = 0, 16): B[k=8*h2+t][i=l31]
    short8 qf0 = *reinterpret_cast<const short8*>(
        qb + ((size_t)b * N_ + i0 + l31) * INTER_ + 8 * h2);
    short8 qf1 = *reinterpret_cast<const short8*>(
        qb + ((size_t)b * N_ + i0 + l31) * INTER_ + 8 * h2 + 16);

    f32x16 acc[8];
    #pragma unroll
    for (int g = 0; g < 8; ++g)
        #pragma unroll
        for (int r = 0; r < 16; ++r) acc[g][r] = 0.f;

    float m_run = 0.f;   // defer-max init; slow path fixes if s grows
    float l_run = 0.f;

    const int jbeg = wave * (N_ / 4);
    const f32x16 z16 = {};

    for (int jt = 0; jt < (N_ / 4) / 32; ++jt) {
        const int j0 = jbeg + jt * 32;

        // K A-fragments: A[row=j=l31][k=8*h2+t]
        short8 ka0 = *reinterpret_cast<const short8*>(
            kbb + (size_t)(j0 + l31) * INTER_ + 8 * h2);
        short8 ka1 = *reinterpret_cast<const short8*>(
            kbb + (size_t)(j0 + l31) * INTER_ + 8 * h2 + 16);

        f32x16 s = __builtin_amdgcn_mfma_f32_32x32x16_bf16(ka0, qf0, z16, 0, 0, 0);
        s = __builtin_amdgcn_mfma_f32_32x32x16_bf16(ka1, qf1, s, 0, 0, 0);
        // lane holds S^T[j_loc][i=l31], j_loc(r) = (r&3) + 8*(r>>2) + 4*h2

        float a0 = fmaxf(s[0], s[8]),  a1 = fmaxf(s[1], s[9]);
        float a2 = fmaxf(s[2], s[10]), a3 = fmaxf(s[3], s[11]);
        float a4 = fmaxf(s[4], s[12]), a5 = fmaxf(s[5], s[13]);
        float a6 = fmaxf(s[6], s[14]), a7 = fmaxf(s[7], s[15]);
        a0 = fmaxf(a0, a4); a1 = fmaxf(a1, a5); a2 = fmaxf(a2, a6); a3 = fmaxf(a3, a7);
        float smax = fmaxf(fmaxf(a0, a1), fmaxf(a2, a3));

        if (__any(smax > m_run + 5.5f)) {    // defer-max: rare slow path
            float sm2 = fmaxf(smax, __shfl_xor(smax, 32));
            float mnew = fmaxf(m_run, sm2);
            float corr = __expf(m_run - mnew);
            m_run = mnew;
            l_run *= corr;
            #pragma unroll
            for (int g = 0; g < 8; ++g)
                #pragma unroll
                for (int r = 0; r < 16; ++r) acc[g][r] *= corr;
        }

        float p[16];
        float lsum = 0.f;
        #pragma unroll
        for (int r = 0; r < 16; ++r) { p[r] = __expf(s[r] - m_run); lsum += p[r]; }
        l_run += lsum;

        unsigned int X0 = cvtpk(p[0],  p[1]),  X1 = cvtpk(p[2],  p[3]);
        unsigned int Y0 = cvtpk(p[4],  p[5]),  Y1 = cvtpk(p[6],  p[7]);
        unsigned int W0 = cvtpk(p[8],  p[9]),  W1 = cvtpk(p[10], p[11]);
        unsigned int V0 = cvtpk(p[12], p[13]), V1 = cvtpk(p[14], p[15]);
        pl32swap(X0, Y0); pl32swap(X1, Y1);
        pl32swap(W0, V0); pl32swap(W1, V1);
        short8 pb0 = __builtin_bit_cast(short8, u32x4{X0, X1, Y0, Y1});
        short8 pb1 = __builtin_bit_cast(short8, u32x4{W0, W1, V0, V1});

        __builtin_amdgcn_s_setprio(1);
        #pragma unroll
        for (int g = 0; g < 8; ++g) {
            const unsigned short* vrow = vtb + (size_t)(32 * g + l31) * N_ + j0 + 8 * h2;
            short8 va0 = *reinterpret_cast<const short8*>(vrow);
            short8 va1 = *reinterpret_cast<const short8*>(vrow + 16);
            acc[g] = __builtin_amdgcn_mfma_f32_32x32x16_bf16(va0, pb0, acc[g], 0, 0, 0);
            acc[g] = __builtin_amdgcn_mfma_f32_32x32x16_bf16(va1, pb1, acc[g], 0, 0, 0);
        }
        __builtin_amdgcn_s_setprio(0);
    }

    // ---- combine: m/l merge, then phased acc merge through 32KB buf ----
    float l_tot = l_run + __shfl_xor(l_run, 32);
    if (lane < 32) { m_sh[wave][lane] = m_run; l_sh[wave][lane] = l_tot; }
    __syncthreads();

    const float M = fmaxf(fmaxf(m_sh[0][l31], m_sh[1][l31]),
                          fmaxf(m_sh[2][l31], m_sh[3][l31]));
    float L = 0.f;
    #pragma unroll
    for (int w = 0; w < 4; ++w) L += __expf(m_sh[w][l31] - M) * l_sh[w][l31];
    const float wgt = __expf(m_run - M);

    #pragma unroll
    for (int g = 0; g < 8; ++g)
        #pragma unroll
        for (int r = 0; r < 16; ++r) acc[g][r] *= wgt;

    for (int w = 1; w < 4; ++w) {
        if (wave == w) {
            #pragma unroll
            for (int g = 0; g < 8; ++g)
                #pragma unroll
                for (int r4 = 0; r4 < 4; ++r4) {
                    f32x4 t;
                    #pragma unroll
                    for (int e = 0; e < 4; ++e) t[e] = acc[g][4 * r4 + e];
                    buf[(g * 4 + r4) * 64 + lane] = t;
                }
        }
        __syncthreads();
        if (wave == 0) {
            #pragma unroll
            for (int g = 0; g < 8; ++g)
                #pragma unroll
                for (int r4 = 0; r4 < 4; ++r4) {
                    f32x4 t = buf[(g * 4 + r4) * 64 + lane];
                    #pragma unroll
                    for (int e = 0; e < 4; ++e) acc[g][4 * r4 + e] += t[e];
                }
        }
        __syncthreads();
    }
    if (wave == 0) {
        #pragma unroll
        for (int g = 0; g < 8; ++g)
            #pragma unroll
            for (int r4 = 0; r4 < 4; ++r4) {
                f32x4 t;
                #pragma unroll
                for (int e = 0; e < 4; ++e) t[e] = acc[g][4 * r4 + e];
                buf[(g * 4 + r4) * 64 + lane] = t;
            }
    }
    __syncthreads();

    // ---- epilogue: all waves store 2 c-groups each ----
    const float gma  = gamma[0];
    const float invL = 1.f / L;
    #pragma unroll
    for (int gi = 0; gi < 2; ++gi) {
        const int gg = 2 * wave + gi;
        #pragma unroll
        for (int r4 = 0; r4 < 4; ++r4) {
            f32x4 v = buf[(gg * 4 + r4) * 64 + lane];
            #pragma unroll
            for (int e = 0; e < 4; ++e) {
                const int c = 32 * gg + e + 8 * r4 + 4 * h2;
                const size_t off = ((size_t)b * C_ + c) * N_ + i0 + l31;
                out[off] = gma * v[e] * invL + x[off];
            }
        }
    }
}

extern "C" void kernel_launch(void* const* d_in, const int* in_sizes, int n_in,
                              void* d_out, int out_size, void* d_ws, size_t ws_size,
                              hipStream_t stream) {
    const float* x     = (const float*)d_in[0];
    const float* Wq    = (const float*)d_in[1];
    const float* bq    = (const float*)d_in[2];
    const float* Wk    = (const float*)d_in[3];
    const float* bk    = (const float*)d_in[4];
    const float* Wv    = (const float*)d_in[5];
    const float* bv    = (const float*)d_in[6];
    const float* gamma = (const float*)d_in[7];
    float* out = (float*)d_out;

    unsigned short* ws = (unsigned short*)d_ws;
    unsigned short* qb = ws;                                   // B*N*32 bf16
    unsigned short* kb = qb + (size_t)B_ * N_ * INTER_;        // B*N*32 bf16
    unsigned short* vt = kb + (size_t)B_ * N_ * INTER_;        // B*C*N bf16 (transposed)
    unsigned short* wb = vt + (size_t)B_ * C_ * N_;            // 320*256 bf16

    prep_kernel<<<dim3(320), 256, 0, stream>>>(Wq, Wk, Wv, wb);
    qkv_kernel<<<dim3(B_ * (N_ / 64)), 256, 0, stream>>>(
        x, wb, bq, bk, bv, qb, kb, vt);
    attn_kernel<<<dim3(N_ / 32, B_), 256, 0, stream>>>(
        qb, kb, vt, x, gamma, out);
}